// Round 4
// baseline (148.924 us; speedup 1.0000x reference)
//
#include <hip/hip_runtime.h>
#include <math.h>

#define HW    16384
#define NTOK  32768
#define CDIM  128
#define HFDIM 512
#define NEXP  6

typedef __attribute__((ext_vector_type(8))) short short8;
typedef __attribute__((ext_vector_type(8))) unsigned short ushort8v;
typedef __attribute__((ext_vector_type(16))) float f32x16;
typedef unsigned long long u64;

// workspace byte offsets (256-aligned)
#define OFF_XFB    0UL          // N*128 bf16      = 8,388,608
#define OFF_LIST   8388608UL    // E*N int         =   786,432
#define OFF_GATES  9175040UL    // 2N float        =   262,144
#define OFF_OUTBUF 9437184UL    // 2N*128 bf16     = 16,777,216
#define OFF_WT1    42991616UL   // E*4*16384 bf16  =   786,432
#define OFF_WT2    43778048UL   // E*4*16384 bf16  =   786,432
#define OFF_BIAS   44564480UL
#define OFF_CNT    44564736UL
#define OFF_WSUM   44564992UL

__device__ __forceinline__ unsigned int bf16_1(float f) {
    unsigned int u = __float_as_uint(f);
    return (u + 0x7FFFu + ((u >> 16) & 1)) >> 16;
}
__device__ __forceinline__ unsigned int bf16pair(float lo, float hi) {
    return bf16_1(lo) | (bf16_1(hi) << 16);
}
// sigmoid-form gelu: x*sigmoid(1.702x); ~5 VALU inst
__device__ __forceinline__ float gelu_f(float v) {
    return __fdividef(v, 1.0f + __expf(-1.702f * v));
}
// byte offset into a [rows][128 bf16] tile (256 B/row), 16B-slot XOR swizzle
__device__ __forceinline__ int swz(int row, int kcol) {
    return row * 256 + ((((kcol >> 3) ^ row) & 15) << 4) + ((kcol & 7) << 1);
}

#define GLDS16(src, dst) __builtin_amdgcn_global_load_lds( \
    (const __attribute__((address_space(1))) void*)(src),  \
    (__attribute__((address_space(3))) void*)(dst), 16, 0, 0)

__device__ __forceinline__ f32x16 MFMA_B(short8 a, short8 b, f32x16 c) {
    return __builtin_amdgcn_mfma_f32_32x32x16_bf16(a, b, c, 0, 0, 0);
}

// K0: per-batch gating bias + zero atomics (deterministic per call)
__global__ __launch_bounds__(64) void prep_kernel(
    const float* __restrict__ prompt, const float* __restrict__ de_cls,
    const float* __restrict__ w_g, const float* __restrict__ gate_boost,
    const float* __restrict__ degra_w, const float* __restrict__ degra_b,
    float* __restrict__ bias, int* __restrict__ cnt, float* __restrict__ wsum)
{
    int t = threadIdx.x;
    if (t < 2 * NEXP) {
        int b = t / NEXP, e = t % NEXP;
        float acc = 0.f;
        for (int c = 0; c < CDIM; ++c)
            acc = fmaf(prompt[b*CDIM + c], w_g[(CDIM + c)*NEXP + e], acc);
        float db = 0.f;
        for (int d = 0; d < 6; ++d)
            db = fmaf(de_cls[b*6 + d], degra_w[d*NEXP + e], db);
        bias[b*NEXP + e] = acc + gate_boost[0] * (db + degra_b[e]);
    }
    if (t >= 32 && t < 32 + NEXP) cnt[t - 32] = 0;
    if (t >= 40 && t < 40 + NEXP) wsum[t - 40] = 0.f;
}

// Kw: fp32 weights -> bf16, transposed [col][k] pre-swizzled so a LINEAR
// global_load_lds copy yields the swizzled LDS image (rule 21 / m173).
__global__ __launch_bounds__(256) void wconv_kernel(
    const float* __restrict__ fc1_w, const float* __restrict__ fc2_w,
    unsigned short* __restrict__ wt1, unsigned short* __restrict__ wt2)
{
    __shared__ unsigned short ls[128][128];   // [k][col] bf16, 32 KB
    const int bid = blockIdx.x;               // e*8 + which*4 + chunk
    const int e = bid >> 3, which = (bid >> 2) & 1, ch = bid & 3;
    const int t = threadIdx.x;
    #pragma unroll 4
    for (int i = 0; i < 16; ++i) {
        int id = t + 256 * i;                 // 4096 float4 tasks
        int k = id >> 5, q = id & 31;
        const float* p = which
            ? (fc2_w + (size_t)e*65536 + (size_t)(ch*128 + k)*128 + q*4)
            : (fc1_w + (size_t)e*65536 + (size_t)k*512 + ch*128 + q*4);
        float4 v = *(const float4*)p;
        u64 pk = (u64)bf16_1(v.x) | ((u64)bf16_1(v.y) << 16)
               | ((u64)bf16_1(v.z) << 32) | ((u64)bf16_1(v.w) << 48);
        *(u64*)&ls[k][q*4] = pk;
    }
    __syncthreads();
    unsigned short* dst = (which ? wt2 : wt1) + (((size_t)(e*4 + ch)) << 14);
    #pragma unroll 2
    for (int i = 0; i < 8; ++i) {
        int id = t + 256 * i;                 // 2048 tasks: (col, kg)
        int col = id & 127, kg = id >> 7;
        unsigned short v[8];
        #pragma unroll
        for (int j = 0; j < 8; ++j) v[j] = ls[kg*8 + j][col];
        int4 pk;
        pk.x = v[0] | (v[1] << 16); pk.y = v[2] | (v[3] << 16);
        pk.z = v[4] | (v[5] << 16); pk.w = v[6] | (v[7] << 16);
        *(int4*)(dst + (size_t)col*128 + (((kg ^ col) & 15) << 3)) = pk;
    }
}

// K1: transpose x -> xfb (token-major bf16), gating, top-2 softmax, lists.
__global__ __launch_bounds__(256) void gate_kernel(
    const float* __restrict__ x, const float* __restrict__ w_g,
    const float* __restrict__ bias, unsigned short* __restrict__ xfb,
    int* __restrict__ list, float* __restrict__ gates,
    int* __restrict__ cnt, float* __restrict__ wsum)
{
    __shared__ float xs[CDIM][65];
    __shared__ float wgs[CDIM][NEXP];
    __shared__ int   cnt_s[NEXP];
    __shared__ float ws_s[NEXP];
    __shared__ int   base_s[NEXP];
    const int t = threadIdx.x;
    const int n0 = blockIdx.x * 64;
    const int b = n0 >> 14;
    const int hw0 = n0 & (HW - 1);

    for (int i = t; i < CDIM * NEXP; i += 256) wgs[i / NEXP][i % NEXP] = w_g[i];
    if (t < NEXP) { cnt_s[t] = 0; ws_s[t] = 0.f; }

    const float* xb = x + (size_t)b * CDIM * HW + hw0;
    #pragma unroll 4
    for (int i = 0; i < 32; ++i) {
        int idx = t + 256 * i;
        int c = idx >> 6, j = idx & 63;
        xs[c][j] = xb[(size_t)c * HW + j];
    }
    __syncthreads();
    unsigned int* xo = (unsigned int*)xfb;
    #pragma unroll 4
    for (int i = 0; i < 16; ++i) {
        int idx = t + 256 * i;
        int tk = idx >> 6, cp = idx & 63;
        xo[(size_t)(n0 + tk) * 64 + cp] = bf16pair(xs[2*cp][tk], xs[2*cp+1][tk]);
    }

    int i0 = 0, i1 = 0, s0 = 0, s1 = 0;
    float g0 = 0.f, g1 = 0.f;
    if (t < 64) {
        float lg[NEXP];
        #pragma unroll
        for (int e = 0; e < NEXP; ++e) lg[e] = bias[b*NEXP + e];
        for (int c = 0; c < CDIM; ++c) {
            float xv = xs[c][t];
            #pragma unroll
            for (int e = 0; e < NEXP; ++e) lg[e] = fmaf(xv, wgs[c][e], lg[e]);
        }
        i0 = 0;
        #pragma unroll
        for (int e = 1; e < NEXP; ++e) if (lg[e] > lg[i0]) i0 = e;
        i1 = (i0 == 0) ? 1 : 0;
        #pragma unroll
        for (int e = 0; e < NEXP; ++e) if (e != i0 && lg[e] > lg[i1]) i1 = e;
        float e1 = expf(lg[i1] - lg[i0]);
        g0 = 1.f / (1.f + e1);
        g1 = e1 * g0;
        s0 = atomicAdd(&cnt_s[i0], 1);
        s1 = atomicAdd(&cnt_s[i1], 1);
        atomicAdd(&ws_s[i0], g0);
        atomicAdd(&ws_s[i1], g1);
    }
    __syncthreads();
    if (t < NEXP) {
        base_s[t] = atomicAdd(&cnt[t], cnt_s[t]);
        atomicAdd(&wsum[t], ws_s[t]);
    }
    __syncthreads();
    if (t < 64) {
        int n = n0 + t;
        list[i0 * NTOK + base_s[i0] + s0] = 2 * n;
        list[i1 * NTOK + base_s[i1] + s1] = 2 * n + 1;
        gates[2 * n]     = g0;
        gates[2 * n + 1] = g1;
    }
}

// K2: balance loss
__global__ void loss_kernel(const int* __restrict__ cnt,
                            const float* __restrict__ wsum,
                            float* __restrict__ out_loss)
{
    if (threadIdx.x == 0 && blockIdx.x == 0) {
        float mw = 0.f, mc = 0.f;
        for (int e = 0; e < NEXP; ++e) { mw += wsum[e]; mc += (float)cnt[e]; }
        mw /= NEXP; mc /= NEXP;
        float vw = 0.f, vc = 0.f;
        for (int e = 0; e < NEXP; ++e) {
            float dw = wsum[e] - mw, dc = (float)cnt[e] - mc;
            vw += dw * dw; vc += dc * dc;
        }
        vw /= (NEXP - 1); vc /= (NEXP - 1);
        out_loss[0] = vw / (mw * mw + 1e-10f) + vc / (mc * mc + 1e-10f);
    }
}

// K3: MFMA expert MLP. 256-token tiles, 8 waves (512 thr), 128 KB LDS,
// 1 block/CU. Wave (w&3) = 64-token quarter, (w>>2) = 64-wide hf/c half.
// Per 128-hf chunk: co-stage W1c->wbA + W2c->wbB (ONE drain), GEMM1,
// gelu + direct b16 writes to hs, GEMM2. 3 barriers/chunk.
__global__ __launch_bounds__(512, 2) void expert_kernel(
    const unsigned short* __restrict__ xfb, const int* __restrict__ list,
    const int* __restrict__ cnt, const float* __restrict__ gates,
    const unsigned short* __restrict__ wt1, const unsigned short* __restrict__ wt2,
    const float* __restrict__ fc1_b, const float* __restrict__ fc2_b,
    unsigned short* __restrict__ outbuf)
{
    __shared__ unsigned short wbA[16384];  // 32 KB: X rows 0-127, then W1 chunk
    __shared__ unsigned short wbB[16384];  // 32 KB: X rows 128-255, then W2 chunk
    __shared__ unsigned short hs[32768];   // 64 KB: hid [256 tok][128 hf] bf16
    const int e = blockIdx.x;
    const int ne = cnt[e];
    const int base = blockIdx.y * 256;
    if (base >= ne) return;
    const int t = threadIdx.x;
    const int w = t >> 6, l = t & 63;

    // row metadata: lane l holds rows base + q*64 + l for q=0..3
    int aq0, aq1, aq2, aq3;
    float gq0, gq1, gq2, gq3;
    int tq0, tq1, tq2, tq3;
    {
        int r;
        r = base + l;       aq0 = (r < ne) ? list[e*NTOK + r] : -1;
        r = base + 64 + l;  aq1 = (r < ne) ? list[e*NTOK + r] : -1;
        r = base + 128 + l; aq2 = (r < ne) ? list[e*NTOK + r] : -1;
        r = base + 192 + l; aq3 = (r < ne) ? list[e*NTOK + r] : -1;
        gq0 = (aq0 >= 0) ? gates[aq0] : 0.f;
        gq1 = (aq1 >= 0) ? gates[aq1] : 0.f;
        gq2 = (aq2 >= 0) ? gates[aq2] : 0.f;
        gq3 = (aq3 >= 0) ? gates[aq3] : 0.f;
        tq0 = (aq0 >= 0) ? (aq0 >> 1) : 0;
        tq1 = (aq1 >= 0) ? (aq1 >> 1) : 0;
        tq2 = (aq2 >= 0) ? (aq2 >> 1) : 0;
        tq3 = (aq3 >= 0) ? (aq3 >> 1) : 0;
    }

    // stage X: wave w stages global rows w*32..w*32+31 (pre-swizzled source)
    {
        int sel = w >> 1;   // rows' quarter
        int tv = (sel == 0) ? tq0 : (sel == 1) ? tq1 : (sel == 2) ? tq2 : tq3;
        unsigned short* xdst = (w < 4) ? wbA : wbB;
        #pragma unroll
        for (int i = 0; i < 8; ++i) {
            int row = w*32 + i*4 + (l >> 4);
            int tok = __shfl(tv, row & 63);
            int slot = (l & 15) ^ (row & 15);
            GLDS16(xfb + (size_t)tok*128 + slot*8, &xdst[(w & 3)*4096 + i*512]);
        }
    }
    __syncthreads();
    // A fragments: token quarter tq = w&3, rows tq*64 + m*32 + (l&31)
    short8 afr[2][8];
    {
        int tq = w & 3;
        const unsigned short* xb = (tq < 2) ? wbA : wbB;
        int rb = (tq & 1)*64 + (l & 31);
        #pragma unroll
        for (int m = 0; m < 2; ++m)
            #pragma unroll
            for (int ks = 0; ks < 8; ++ks)
                afr[m][ks] = *(const short8*)((const char*)xb +
                             swz(rb + m*32, ks*16 + (l >> 5)*8));
    }
    __syncthreads();   // afr in regs; wbA/wbB free for weight staging

    f32x16 zz;
    #pragma unroll
    for (int i = 0; i < 16; ++i) zz[i] = 0.0f;
    f32x16 oacc[2][2] = {zz, zz, zz, zz};

    const int colh = (w >> 2) * 64;   // wave's 64-wide hf/c half base
    const int lk = (l >> 5) * 8;
    const int l31 = l & 31;
    const int trow = (w & 3) * 64;    // wave's token-quarter base row in hs

    for (int hc = 0; hc < 4; ++hc) {
        // co-stage W1 chunk -> wbA and W2 chunk -> wbB (linear copy, one drain)
        {
            const unsigned short* s1 = wt1 + (((size_t)(e*4 + hc)) << 14) + w*2048 + l*8;
            const unsigned short* s2 = wt2 + (((size_t)(e*4 + hc)) << 14) + w*2048 + l*8;
            #pragma unroll
            for (int i = 0; i < 4; ++i)
                GLDS16(s1 + i*512, &wbA[w*2048 + i*512]);
            #pragma unroll
            for (int i = 0; i < 4; ++i)
                GLDS16(s2 + i*512, &wbB[w*2048 + i*512]);
        }
        __syncthreads();
        // GEMM1: hid tile (64 tok x 64 hf), k = C = 128
        f32x16 acc1[2][2] = {zz, zz, zz, zz};
        #pragma unroll
        for (int ks = 0; ks < 8; ++ks) {
            int k = ks*16 + lk;
            #pragma unroll
            for (int nt = 0; nt < 2; ++nt) {
                short8 bfr = *(const short8*)((const char*)wbA +
                             swz(colh + nt*32 + l31, k));
                acc1[0][nt] = MFMA_B(afr[0][ks], bfr, acc1[0][nt]);
                acc1[1][nt] = MFMA_B(afr[1][ks], bfr, acc1[1][nt]);
            }
        }
        // bias + gelu, direct b16 writes into swizzled hs
        #pragma unroll
        for (int m = 0; m < 2; ++m) {
            #pragma unroll
            for (int nt = 0; nt < 2; ++nt) {
                int col = colh + nt*32 + l31;
                float b1 = fc1_b[(size_t)e*HFDIM + hc*128 + col];
                f32x16 v = acc1[m][nt];
                #pragma unroll
                for (int r = 0; r < 16; ++r) {
                    float h = gelu_f(v[r] + b1);
                    int row = trow + m*32 + (r & 3) + 8*(r >> 2) + 4*(l >> 5);
                    *(unsigned short*)((char*)hs + swz(row, col)) =
                        (unsigned short)bf16_1(h);
                }
            }
        }
        __syncthreads();   // hs complete; wbA reads done
        // GEMM2 partial: out tile (64 tok x 64 c), k = chunk's 128 hid cols
        #pragma unroll
        for (int ks = 0; ks < 8; ++ks) {
            int k = ks*16 + lk;
            short8 a2_0 = *(const short8*)((const char*)hs + swz(trow + l31, k));
            short8 a2_1 = *(const short8*)((const char*)hs + swz(trow + 32 + l31, k));
            #pragma unroll
            for (int nt = 0; nt < 2; ++nt) {
                short8 b2 = *(const short8*)((const char*)wbB +
                            swz(colh + nt*32 + l31, k));
                oacc[0][nt] = MFMA_B(a2_0, b2, oacc[0][nt]);
                oacc[1][nt] = MFMA_B(a2_1, b2, oacc[1][nt]);
            }
        }
        __syncthreads();   // all wbA/wbB/hs reads done -> safe to restage
    }

    // epilogue: gate * exp(out + fc2_b) -> bf16 scatter to outbuf[a]
    float b2f[2];
    #pragma unroll
    for (int nt = 0; nt < 2; ++nt)
        b2f[nt] = fc2_b[(size_t)e*CDIM + colh + nt*32 + l31];
    int tq = w & 3;
    int   asel = (tq == 0) ? aq0 : (tq == 1) ? aq1 : (tq == 2) ? aq2 : aq3;
    float gsel = (tq == 0) ? gq0 : (tq == 1) ? gq1 : (tq == 2) ? gq2 : gq3;
    #pragma unroll
    for (int m = 0; m < 2; ++m) {
        #pragma unroll
        for (int r = 0; r < 16; ++r) {
            int crow = (r & 3) + 8*(r >> 2) + 4*(l >> 5);
            int rloc = m*32 + crow;
            int av   = __shfl(asel, rloc);
            float gv = __shfl(gsel, rloc);
            if (av < 0) continue;
            #pragma unroll
            for (int nt = 0; nt < 2; ++nt) {
                int col = colh + nt*32 + l31;
                outbuf[(size_t)av*CDIM + col] =
                    (unsigned short)bf16_1(gv * __expf(oacc[m][nt][r] + b2f[nt]));
            }
        }
    }
}

// K4: y = log(p0 + p1) from bf16 partials, transpose back to (B,C,H,W)
__global__ __launch_bounds__(256) void combine_kernel(
    const unsigned short* __restrict__ outbuf, float* __restrict__ out)
{
    __shared__ float ys[64][129];
    const int t = threadIdx.x;
    const int n0 = blockIdx.x * 64;
    const int b = n0 >> 14;
    const int hw0 = n0 & (HW - 1);
    #pragma unroll
    for (int i = 0; i < 4; ++i) {
        int idx = t + 256 * i;            // 1024 tasks: token x 16-col group
        int tk = idx >> 4, c8 = (idx & 15) * 8;
        const unsigned short* p = outbuf + (size_t)(n0 + tk) * 256 + c8;
        ushort8v p0 = *(const ushort8v*)p;
        ushort8v p1 = *(const ushort8v*)(p + 128);
        const float EPSL = 2.2204460492503131e-16f;
        #pragma unroll
        for (int j = 0; j < 8; ++j) {
            float v = __uint_as_float((unsigned)p0[j] << 16)
                    + __uint_as_float((unsigned)p1[j] << 16);
            ys[tk][c8 + j] = __logf(v == 0.f ? EPSL : v);
        }
    }
    __syncthreads();
    float* ob = out + (size_t)b * CDIM * HW + hw0;
    #pragma unroll 4
    for (int i = 0; i < 32; ++i) {
        int idx = t + 256 * i;
        int c = idx >> 6;
        int j = idx & 63;
        ob[(size_t)c * HW + j] = ys[j][c];
    }
}

extern "C" void kernel_launch(void* const* d_in, const int* in_sizes, int n_in,
                              void* d_out, int out_size, void* d_ws, size_t ws_size,
                              hipStream_t stream)
{
    const float* x       = (const float*)d_in[0];
    const float* prompt  = (const float*)d_in[1];
    const float* de_cls  = (const float*)d_in[2];
    const float* w_g     = (const float*)d_in[3];
    const float* gboost  = (const float*)d_in[4];
    const float* degra_w = (const float*)d_in[5];
    const float* degra_b = (const float*)d_in[6];
    const float* fc1_w   = (const float*)d_in[7];
    const float* fc1_b   = (const float*)d_in[8];
    const float* fc2_w   = (const float*)d_in[9];
    const float* fc2_b   = (const float*)d_in[10];
    float* out = (float*)d_out;
    char* ws = (char*)d_ws;

    unsigned short* xfb  = (unsigned short*)(ws + OFF_XFB);
    int*   list   = (int*)(ws + OFF_LIST);
    float* gates  = (float*)(ws + OFF_GATES);
    unsigned short* outbuf = (unsigned short*)(ws + OFF_OUTBUF);
    unsigned short* wt1 = (unsigned short*)(ws + OFF_WT1);
    unsigned short* wt2 = (unsigned short*)(ws + OFF_WT2);
    float* bias   = (float*)(ws + OFF_BIAS);
    int*   cnt    = (int*)(ws + OFF_CNT);
    float* wsum   = (float*)(ws + OFF_WSUM);

    prep_kernel<<<1, 64, 0, stream>>>(prompt, de_cls, w_g, gboost, degra_w,
                                      degra_b, bias, cnt, wsum);
    wconv_kernel<<<48, 256, 0, stream>>>(fc1_w, fc2_w, wt1, wt2);
    gate_kernel<<<512, 256, 0, stream>>>(x, w_g, bias, xfb, list, gates, cnt, wsum);
    loss_kernel<<<1, 64, 0, stream>>>(cnt, wsum, out + (size_t)NTOK * CDIM);
    dim3 eg(NEXP, 128);   // 256-token tiles; covers ne up to 32768
    expert_kernel<<<eg, 512, 0, stream>>>(xfb, list, cnt, gates, wt1, wt2,
                                          fc1_b, fc2_b, outbuf);
    combine_kernel<<<512, 256, 0, stream>>>(outbuf, out);
}

// Round 6
// 103.670 us; speedup vs baseline: 1.4365x; 1.4365x over previous
//
#include <hip/hip_runtime.h>
#include <math.h>

#define HW    16384
#define NTOK  32768
#define CDIM  128
#define HFDIM 512
#define NEXP  6

typedef __attribute__((ext_vector_type(8))) short short8;
typedef __attribute__((ext_vector_type(8))) unsigned short ushort8v;
typedef __attribute__((ext_vector_type(16))) float f32x16;
typedef unsigned long long u64;

// workspace byte offsets (256-aligned)
#define OFF_XFB    0UL          // N*128 bf16      = 8,388,608
#define OFF_LIST   8388608UL    // E*N int         =   786,432
#define OFF_GATES  9175040UL    // 2N float        =   262,144
#define OFF_OUTBUF 9437184UL    // 2N*128 bf16     = 16,777,216
#define OFF_WT1    42991616UL   // E*4*16384 bf16  =   786,432
#define OFF_WT2    43778048UL   // E*8*8192 bf16   =   786,432
#define OFF_BIAS   44564480UL
#define OFF_CNT    44564736UL
#define OFF_WSUM   44564992UL

__device__ __forceinline__ unsigned int bf16_1(float f) {
    unsigned int u = __float_as_uint(f);
    return (u + 0x7FFFu + ((u >> 16) & 1)) >> 16;
}
__device__ __forceinline__ unsigned int bf16pair(float lo, float hi) {
    return bf16_1(lo) | (bf16_1(hi) << 16);
}
// sigmoid-form gelu: x*sigmoid(1.702x); ~5 VALU inst
__device__ __forceinline__ float gelu_f(float v) {
    return __fdividef(v, 1.0f + __expf(-1.702f * v));
}

#define GLDS16(src, dst) __builtin_amdgcn_global_load_lds( \
    (const __attribute__((address_space(1))) void*)(src),  \
    (__attribute__((address_space(3))) void*)(dst), 16, 0, 0)

__device__ __forceinline__ f32x16 MFMA_B(short8 a, short8 b, f32x16 c) {
    return __builtin_amdgcn_mfma_f32_32x32x16_bf16(a, b, c, 0, 0, 0);
}

// K0: per-batch gating bias + zero atomics (deterministic per call)
__global__ __launch_bounds__(64) void prep_kernel(
    const float* __restrict__ prompt, const float* __restrict__ de_cls,
    const float* __restrict__ w_g, const float* __restrict__ gate_boost,
    const float* __restrict__ degra_w, const float* __restrict__ degra_b,
    float* __restrict__ bias, int* __restrict__ cnt, float* __restrict__ wsum)
{
    int t = threadIdx.x;
    if (t < 2 * NEXP) {
        int b = t / NEXP, e = t % NEXP;
        float acc = 0.f;
        for (int c = 0; c < CDIM; ++c)
            acc = fmaf(prompt[b*CDIM + c], w_g[(CDIM + c)*NEXP + e], acc);
        float db = 0.f;
        for (int d = 0; d < 6; ++d)
            db = fmaf(de_cls[b*6 + d], degra_w[d*NEXP + e], db);
        bias[b*NEXP + e] = acc + gate_boost[0] * (db + degra_b[e]);
    }
    if (t >= 32 && t < 32 + NEXP) cnt[t - 32] = 0;
    if (t >= 40 && t < 40 + NEXP) wsum[t - 40] = 0.f;
}

// Kw: fp32 weights -> bf16, transposed + pre-swizzled so LINEAR global_load_lds
// copies yield the swizzled LDS image (rule 21 / m173).
// wt1: [e][ch=hf/128][hfcol 128][k 128] rows 256B, 16-slot XOR (hfcol&15).
// wt2: [e][kc=k/64][c 128][k 64] rows 128B, 8-slot XOR (c&7).
__global__ __launch_bounds__(256) void wconv_kernel(
    const float* __restrict__ fc1_w, const float* __restrict__ fc2_w,
    unsigned short* __restrict__ wt1, unsigned short* __restrict__ wt2)
{
    __shared__ unsigned short ls[128][128];   // [k][col] bf16, 32 KB
    const int bid = blockIdx.x;               // e*8 + which*4 + chunk
    const int e = bid >> 3, which = (bid >> 2) & 1, ch = bid & 3;
    const int t = threadIdx.x;
    #pragma unroll 4
    for (int i = 0; i < 16; ++i) {
        int id = t + 256 * i;                 // 4096 float4 tasks
        int k = id >> 5, q = id & 31;
        const float* p = which
            ? (fc2_w + (size_t)e*65536 + (size_t)(ch*128 + k)*128 + q*4)
            : (fc1_w + (size_t)e*65536 + (size_t)k*512 + ch*128 + q*4);
        float4 v = *(const float4*)p;
        u64 pk = (u64)bf16_1(v.x) | ((u64)bf16_1(v.y) << 16)
               | ((u64)bf16_1(v.z) << 32) | ((u64)bf16_1(v.w) << 48);
        *(u64*)&ls[k][q*4] = pk;
    }
    __syncthreads();
    #pragma unroll 2
    for (int i = 0; i < 8; ++i) {
        int id = t + 256 * i;                 // 2048 tasks: (col, kg)
        int col = id & 127, kg = id >> 7;     // kg = k-group of 8 (0..15)
        unsigned short v[8];
        #pragma unroll
        for (int j = 0; j < 8; ++j) v[j] = ls[kg*8 + j][col];
        int4 pk;
        pk.x = v[0] | (v[1] << 16); pk.y = v[2] | (v[3] << 16);
        pk.z = v[4] | (v[5] << 16); pk.w = v[6] | (v[7] << 16);
        if (which) {
            int h = kg >> 3, ks8 = kg & 7;    // 64-k chunk half, slot in chunk
            *(int4*)(wt2 + (((size_t)(e*8 + ch*2 + h)) << 13)
                     + (size_t)col*64 + (((ks8 ^ (col & 7)) & 7) << 3)) = pk;
        } else {
            *(int4*)(wt1 + (((size_t)(e*4 + ch)) << 14)
                     + (size_t)col*128 + (((kg ^ (col & 15)) & 15) << 3)) = pk;
        }
    }
}

// K1: transpose x -> xfb (token-major bf16), gating, top-2 softmax, lists.
__global__ __launch_bounds__(256) void gate_kernel(
    const float* __restrict__ x, const float* __restrict__ w_g,
    const float* __restrict__ bias, unsigned short* __restrict__ xfb,
    int* __restrict__ list, float* __restrict__ gates,
    int* __restrict__ cnt, float* __restrict__ wsum)
{
    __shared__ float xs[CDIM][65];
    __shared__ float wgs[CDIM][NEXP];
    __shared__ int   cnt_s[NEXP];
    __shared__ float ws_s[NEXP];
    __shared__ int   base_s[NEXP];
    const int t = threadIdx.x;
    const int n0 = blockIdx.x * 64;
    const int b = n0 >> 14;
    const int hw0 = n0 & (HW - 1);

    for (int i = t; i < CDIM * NEXP; i += 256) wgs[i / NEXP][i % NEXP] = w_g[i];
    if (t < NEXP) { cnt_s[t] = 0; ws_s[t] = 0.f; }

    const float* xb = x + (size_t)b * CDIM * HW + hw0;
    #pragma unroll 4
    for (int i = 0; i < 32; ++i) {
        int idx = t + 256 * i;
        int c = idx >> 6, j = idx & 63;
        xs[c][j] = xb[(size_t)c * HW + j];
    }
    __syncthreads();
    unsigned int* xo = (unsigned int*)xfb;
    #pragma unroll 4
    for (int i = 0; i < 16; ++i) {
        int idx = t + 256 * i;
        int tk = idx >> 6, cp = idx & 63;
        xo[(size_t)(n0 + tk) * 64 + cp] = bf16pair(xs[2*cp][tk], xs[2*cp+1][tk]);
    }

    int i0 = 0, i1 = 0, s0 = 0, s1 = 0;
    float g0 = 0.f, g1 = 0.f;
    if (t < 64) {
        float lg[NEXP];
        #pragma unroll
        for (int e = 0; e < NEXP; ++e) lg[e] = bias[b*NEXP + e];
        for (int c = 0; c < CDIM; ++c) {
            float xv = xs[c][t];
            #pragma unroll
            for (int e = 0; e < NEXP; ++e) lg[e] = fmaf(xv, wgs[c][e], lg[e]);
        }
        i0 = 0;
        #pragma unroll
        for (int e = 1; e < NEXP; ++e) if (lg[e] > lg[i0]) i0 = e;
        i1 = (i0 == 0) ? 1 : 0;
        #pragma unroll
        for (int e = 0; e < NEXP; ++e) if (e != i0 && lg[e] > lg[i1]) i1 = e;
        float e1 = expf(lg[i1] - lg[i0]);
        g0 = 1.f / (1.f + e1);
        g1 = e1 * g0;
        s0 = atomicAdd(&cnt_s[i0], 1);
        s1 = atomicAdd(&cnt_s[i1], 1);
        atomicAdd(&ws_s[i0], g0);
        atomicAdd(&ws_s[i1], g1);
    }
    __syncthreads();
    if (t < NEXP) {
        base_s[t] = atomicAdd(&cnt[t], cnt_s[t]);
        atomicAdd(&wsum[t], ws_s[t]);
    }
    __syncthreads();
    if (t < 64) {
        int n = n0 + t;
        list[i0 * NTOK + base_s[i0] + s0] = 2 * n;
        list[i1 * NTOK + base_s[i1] + s1] = 2 * n + 1;
        gates[2 * n]     = g0;
        gates[2 * n + 1] = g1;
    }
}

// K2: balance loss
__global__ void loss_kernel(const int* __restrict__ cnt,
                            const float* __restrict__ wsum,
                            float* __restrict__ out_loss)
{
    if (threadIdx.x == 0 && blockIdx.x == 0) {
        float mw = 0.f, mc = 0.f;
        for (int e = 0; e < NEXP; ++e) { mw += wsum[e]; mc += (float)cnt[e]; }
        mw /= NEXP; mc /= NEXP;
        float vw = 0.f, vc = 0.f;
        for (int e = 0; e < NEXP; ++e) {
            float dw = wsum[e] - mw, dc = (float)cnt[e] - mc;
            vw += dw * dw; vc += dc * dc;
        }
        vw /= (NEXP - 1); vc /= (NEXP - 1);
        out_loss[0] = vw / (mw * mw + 1e-10f) + vc / (mc * mc + 1e-10f);
    }
}

// K3: MFMA expert MLP. 64-token tiles, 4 waves, 40 KB LDS -> 4 blocks/CU
// (16 waves/CU): four independent phase-machines per CU so one block's
// stage/drain overlaps another's MFMA/VALU (m114). X goes straight to regs.
// Wave (w&1) = 32-token half, (w>>1) = hf/c half.
__global__ __launch_bounds__(256, 4) void expert_kernel(
    const unsigned short* __restrict__ xfb, const int* __restrict__ list,
    const int* __restrict__ cnt, const float* __restrict__ gates,
    const unsigned short* __restrict__ wt1, const unsigned short* __restrict__ wt2,
    const float* __restrict__ fc1_b, const float* __restrict__ fc2_b,
    unsigned short* __restrict__ outbuf)
{
    __shared__ unsigned short w1c[8192];   // 16 KB [64 hf][128 k] swz16
    __shared__ unsigned short w2c[8192];   // 16 KB [128 c][64 k]  swz8
    __shared__ unsigned short hs[4096];    //  8 KB [64 tok][64 hf] swz8
    const int e = blockIdx.x;
    const int ne = cnt[e];
    const int base = blockIdx.y * 64;
    if (base >= ne) return;
    const int t = threadIdx.x;
    const int w = t >> 6, l = t & 63;
    const int l31 = l & 31, lk = (l >> 5) * 8;
    const int th = (w & 1) * 32;          // token-half base row
    const int hfh = w >> 1;               // hf/c half

    int r = base + l;
    int a = (r < ne) ? list[e*NTOK + r] : -1;
    float g = (a >= 0) ? gates[a] : 0.f;
    int tok = (a >= 0) ? (a >> 1) : 0;

    // A fragments straight from global: row = th + l31, k = ks*16 + lk
    short8 afr[8];
    {
        int tokv = __shfl(tok, th + l31);
        const unsigned short* xr = xfb + (size_t)tokv*128 + lk;
        #pragma unroll
        for (int ks = 0; ks < 8; ++ks)
            afr[ks] = *(const short8*)(xr + ks*16);
    }

    f32x16 zz;
    #pragma unroll
    for (int i = 0; i < 16; ++i) zz[i] = 0.0f;
    f32x16 oacc0 = zz, oacc1 = zz;

    for (int j = 0; j < 8; ++j) {
        // co-stage W1 sub-chunk (64 hf) + W2 chunk (64 k): linear 16KB each.
        // NOTE: global source MUST be per-lane (+ l*8); LDS dest is
        // wave-uniform base (+ lane*16 in hardware).  <- r5 bug was here
        {
            const unsigned short* s1 = wt1 + (((size_t)(e*4 + (j >> 1))) << 14)
                                     + (j & 1)*8192 + (w*4)*512 + l*8;
            const unsigned short* s2 = wt2 + (((size_t)(e*8 + j)) << 13)
                                     + (w*4)*512 + l*8;
            #pragma unroll
            for (int i = 0; i < 4; ++i)
                GLDS16(s1 + i*512, &w1c[(w*4 + i)*512]);
            #pragma unroll
            for (int i = 0; i < 4; ++i)
                GLDS16(s2 + i*512, &w2c[(w*4 + i)*512]);
        }
        __syncthreads();
        // GEMM1: 32 tok x 32 hf, k = 128
        f32x16 acc1 = zz;
        {
            int brow = hfh*32 + l31;
            #pragma unroll
            for (int ks = 0; ks < 8; ++ks) {
                int k = ks*16 + lk;
                short8 bfr = *(const short8*)((const char*)w1c + brow*256
                             + ((((k >> 3) ^ brow) & 15) << 4));
                acc1 = MFMA_B(afr[ks], bfr, acc1);
            }
        }
        // bias + gelu -> hs (swizzled b16 writes)
        {
            int col = hfh*32 + l31;           // hf col within chunk (0..63)
            float b1 = fc1_b[(size_t)e*HFDIM + j*64 + col];
            #pragma unroll
            for (int rr = 0; rr < 16; ++rr) {
                float h = gelu_f(acc1[rr] + b1);
                int row = th + (rr & 3) + 8*(rr >> 2) + 4*(l >> 5);
                *(unsigned short*)((char*)hs + row*128
                    + ((((col >> 3) ^ (row & 7)) & 7) << 4) + ((col & 7) << 1))
                    = (unsigned short)bf16_1(h);
            }
        }
        __syncthreads();
        // GEMM2: 32 tok x 64 c, k = 64 (this chunk's hf slice)
        {
            int arow = th + l31;
            #pragma unroll
            for (int ks = 0; ks < 4; ++ks) {
                int k = ks*16 + lk;
                short8 a2 = *(const short8*)((const char*)hs + arow*128
                             + ((((k >> 3) ^ (arow & 7)) & 7) << 4));
                int crow0 = hfh*64 + l31;
                int crow1 = hfh*64 + 32 + l31;
                short8 b20 = *(const short8*)((const char*)w2c + crow0*128
                             + ((((k >> 3) ^ (crow0 & 7)) & 7) << 4));
                short8 b21 = *(const short8*)((const char*)w2c + crow1*128
                             + ((((k >> 3) ^ (crow1 & 7)) & 7) << 4));
                oacc0 = MFMA_B(a2, b20, oacc0);
                oacc1 = MFMA_B(a2, b21, oacc1);
            }
        }
        __syncthreads();
    }

    // epilogue: gate * exp(out + fc2_b) -> bf16 scatter to outbuf[a]
    float b20 = fc2_b[(size_t)e*CDIM + hfh*64 + l31];
    float b21 = fc2_b[(size_t)e*CDIM + hfh*64 + 32 + l31];
    #pragma unroll
    for (int rr = 0; rr < 16; ++rr) {
        int crow = (rr & 3) + 8*(rr >> 2) + 4*(l >> 5);
        int rloc = th + crow;
        int av   = __shfl(a, rloc);
        float gv = __shfl(g, rloc);
        if (av < 0) continue;
        unsigned short* po = outbuf + (size_t)av*CDIM + hfh*64 + l31;
        po[0]  = (unsigned short)bf16_1(gv * __expf(oacc0[rr] + b20));
        po[32] = (unsigned short)bf16_1(gv * __expf(oacc1[rr] + b21));
    }
}

// K4: y = log(p0 + p1) from bf16 partials, transpose back to (B,C,H,W)
__global__ __launch_bounds__(256) void combine_kernel(
    const unsigned short* __restrict__ outbuf, float* __restrict__ out)
{
    __shared__ float ys[64][129];
    const int t = threadIdx.x;
    const int n0 = blockIdx.x * 64;
    const int b = n0 >> 14;
    const int hw0 = n0 & (HW - 1);
    #pragma unroll
    for (int i = 0; i < 4; ++i) {
        int idx = t + 256 * i;            // 1024 tasks: token x 16-col group
        int tk = idx >> 4, c8 = (idx & 15) * 8;
        const unsigned short* p = outbuf + (size_t)(n0 + tk) * 256 + c8;
        ushort8v p0 = *(const ushort8v*)p;
        ushort8v p1 = *(const ushort8v*)(p + 128);
        const float EPSL = 2.2204460492503131e-16f;
        #pragma unroll
        for (int j = 0; j < 8; ++j) {
            float v = __uint_as_float((unsigned)p0[j] << 16)
                    + __uint_as_float((unsigned)p1[j] << 16);
            ys[tk][c8 + j] = __logf(v == 0.f ? EPSL : v);
        }
    }
    __syncthreads();
    float* ob = out + (size_t)b * CDIM * HW + hw0;
    #pragma unroll 4
    for (int i = 0; i < 32; ++i) {
        int idx = t + 256 * i;
        int c = idx >> 6;
        int j = idx & 63;
        ob[(size_t)c * HW + j] = ys[j][c];
    }
}

extern "C" void kernel_launch(void* const* d_in, const int* in_sizes, int n_in,
                              void* d_out, int out_size, void* d_ws, size_t ws_size,
                              hipStream_t stream)
{
    const float* x       = (const float*)d_in[0];
    const float* prompt  = (const float*)d_in[1];
    const float* de_cls  = (const float*)d_in[2];
    const float* w_g     = (const float*)d_in[3];
    const float* gboost  = (const float*)d_in[4];
    const float* degra_w = (const float*)d_in[5];
    const float* degra_b = (const float*)d_in[6];
    const float* fc1_w   = (const float*)d_in[7];
    const float* fc1_b   = (const float*)d_in[8];
    const float* fc2_w   = (const float*)d_in[9];
    const float* fc2_b   = (const float*)d_in[10];
    float* out = (float*)d_out;
    char* ws = (char*)d_ws;

    unsigned short* xfb  = (unsigned short*)(ws + OFF_XFB);
    int*   list   = (int*)(ws + OFF_LIST);
    float* gates  = (float*)(ws + OFF_GATES);
    unsigned short* outbuf = (unsigned short*)(ws + OFF_OUTBUF);
    unsigned short* wt1 = (unsigned short*)(ws + OFF_WT1);
    unsigned short* wt2 = (unsigned short*)(ws + OFF_WT2);
    float* bias   = (float*)(ws + OFF_BIAS);
    int*   cnt    = (int*)(ws + OFF_CNT);
    float* wsum   = (float*)(ws + OFF_WSUM);

    prep_kernel<<<1, 64, 0, stream>>>(prompt, de_cls, w_g, gboost, degra_w,
                                      degra_b, bias, cnt, wsum);
    wconv_kernel<<<48, 256, 0, stream>>>(fc1_w, fc2_w, wt1, wt2);
    gate_kernel<<<512, 256, 0, stream>>>(x, w_g, bias, xfb, list, gates, cnt, wsum);
    loss_kernel<<<1, 64, 0, stream>>>(cnt, wsum, out + (size_t)NTOK * CDIM);
    dim3 eg(NEXP, 512);   // 64-token tiles; covers ne up to 32768
    expert_kernel<<<eg, 256, 0, stream>>>(xfb, list, cnt, gates, wt1, wt2,
                                          fc1_b, fc2_b, outbuf);
    combine_kernel<<<512, 256, 0, stream>>>(outbuf, out);
}